// Round 4
// baseline (11879.410 us; speedup 1.0000x reference)
//
#include <hip/hip_runtime.h>
#include <hip/hip_bf16.h>

// SSNet: 2-layer flag-gated LSTM, persistent-tile MFMA implementation.
// B=16384, T=32, IN=64, H=512, OUT=19.
// R4 = R3 with the state-roundtrip stride bug fixed: per-(wave,sb) state
// block is 256 floats (16x16 tile), not 1024. R3 wrote at stride 1024,
// overflowing the per-WG region (cross-WG trample) while the refill
// decoded stride 256 -> garbage h (absmax 1.6e5).

#define T_STEPS 32
#define IN_F    64
#define HID     512
#define OUT_F   19
#define BW      64   // batch rows per WG

typedef short bf16x8 __attribute__((ext_vector_type(8)));   // 8 bf16 = 4 VGPRs
typedef float f32x4  __attribute__((ext_vector_type(4)));

__device__ __forceinline__ float fast_sig(float x) {
    return __builtin_amdgcn_rcpf(1.0f + __expf(-x));
}
__device__ __forceinline__ float fast_tanh(float x) {
    return 1.0f - 2.0f * __builtin_amdgcn_rcpf(1.0f + __expf(2.0f * x));
}

// Packed B layout, per 16-col block cb of the 2048 gate-cols:
//   dst[cb*(K*16) + kc*512 + l15*32 + lq*8 + e] = W[kc*32+lq*8+e + rowOff][cb*16+l15]
// so one wave's load per (cb,kc) is 16 lanes x 64B = 1KB contiguous.
__global__ void wprep_kernel(const float* __restrict__ src,
                             __hip_bfloat16* __restrict__ dst,
                             int kcBits, int rowOff) {
    int idx = blockIdx.x * 256 + threadIdx.x;
    int total = 2048 << (kcBits + 5);          // 2048 cols * K, K = 32<<kcBits
    if (idx >= total) return;
    int e   = idx & 7;
    int lq  = (idx >> 3) & 3;
    int l15 = (idx >> 5) & 15;
    int kc  = (idx >> 9) & ((1 << kcBits) - 1);
    int cb  = idx >> (9 + kcBits);
    int k   = kc * 32 + lq * 8 + e + rowOff;
    int col = cb * 16 + l15;
    dst[idx] = __float2bfloat16(src[(size_t)k * 2048 + col]);
}

// acc[g] += A(16 rows from LDS) x B(packed global), 16x16x32 bf16 MFMA
template<int KC>
__device__ __forceinline__ void gemm_acc(const char* __restrict__ alds,
                                         const __hip_bfloat16* __restrict__ Bp,
                                         f32x4 acc[4],
                                         int arowRS, int asw, int lq16,
                                         int laneoff, int cgsb) {
    const __hip_bfloat16* bp0 = Bp + (size_t)(0 * 32 + cgsb) * (KC * 512) + laneoff;
    const __hip_bfloat16* bp1 = Bp + (size_t)(1 * 32 + cgsb) * (KC * 512) + laneoff;
    const __hip_bfloat16* bp2 = Bp + (size_t)(2 * 32 + cgsb) * (KC * 512) + laneoff;
    const __hip_bfloat16* bp3 = Bp + (size_t)(3 * 32 + cgsb) * (KC * 512) + laneoff;
    #pragma unroll 2
    for (int kc = 0; kc < KC; ++kc) {
        bf16x8 a  = *(const bf16x8*)(alds + arowRS + ((kc * 64 + lq16) ^ asw));
        bf16x8 b0 = *(const bf16x8*)(bp0 + kc * 512);
        bf16x8 b1 = *(const bf16x8*)(bp1 + kc * 512);
        bf16x8 b2 = *(const bf16x8*)(bp2 + kc * 512);
        bf16x8 b3 = *(const bf16x8*)(bp3 + kc * 512);
        acc[0] = __builtin_amdgcn_mfma_f32_16x16x32_bf16(a, b0, acc[0], 0, 0, 0);
        acc[1] = __builtin_amdgcn_mfma_f32_16x16x32_bf16(a, b1, acc[1], 0, 0, 0);
        acc[2] = __builtin_amdgcn_mfma_f32_16x16x32_bf16(a, b2, acc[2], 0, 0, 0);
        acc[3] = __builtin_amdgcn_mfma_f32_16x16x32_bf16(a, b3, acc[3], 0, 0, 0);
    }
}

__global__ __launch_bounds__(1024, 4)
void lstm_main(const float* __restrict__ x,
               const float* __restrict__ b0v,
               const float* __restrict__ Wx1,     // row 0 = flag weights (f32)
               const float* __restrict__ b1v,
               const float* __restrict__ Wlin,
               const float* __restrict__ blin,
               const __hip_bfloat16* __restrict__ Wx0p,
               const __hip_bfloat16* __restrict__ Wh0p,
               const __hip_bfloat16* __restrict__ Wx1hp,
               const __hip_bfloat16* __restrict__ Wh1p,
               float* __restrict__ cws,
               float* __restrict__ hws,
               float* __restrict__ out)
{
    // LDS h tiles: row-major bf16, row stride 1024B, XOR-swizzle (row&7)<<4
    __shared__ __align__(16) __hip_bfloat16 h0s[BW * HID];   // 64 KB
    __shared__ __align__(16) __hip_bfloat16 h1s[BW * HID];   // 64 KB
    __shared__ __align__(16) __hip_bfloat16 xs[BW * IN_F];   // 8 KB, row stride 128B
    __shared__ float flags[BW];

    const int tid  = threadIdx.x;
    const int lane = tid & 63;
    const int wid  = tid >> 6;      // 0..15
    const int rg   = wid >> 2;      // row-group: rows rg*16..rg*16+15
    const int cg   = wid & 3;       // col-group: gate-cols cg*128..+127 (per gate)
    const int l15  = lane & 15;
    const int lq   = lane >> 4;
    const int lq16 = lq * 16;
    const int laneoff = l15 * 32 + lq * 8;     // elems within packed 512-elem kc block
    const int arow = rg * 16 + l15;
    const int asw  = (arow & 7) << 4;
    const int wg   = blockIdx.x;
    const size_t bbase = (size_t)wg * BW;

    // zero h LDS
    {
        int4 z; z.x = z.y = z.z = z.w = 0;
        int4* p0 = (int4*)h0s; int4* p1 = (int4*)h1s;
        for (int i = tid; i < BW * HID * 2 / 16; i += 1024) { p0[i] = z; p1[i] = z; }
    }
    // stage x(0) + flags
    for (int i = tid; i < BW * IN_F; i += 1024) {
        int row = i >> 6, k = i & 63;
        float v = x[(bbase + row) * (T_STEPS * IN_F) + k];
        int byte = row * 128 + ((2 * k) ^ ((row & 7) << 4));
        *(__hip_bfloat16*)((char*)xs + byte) = __float2bfloat16(v);
    }
    if (tid < BW) flags[tid] = x[(bbase + tid) * (T_STEPS * IN_F)];
    __syncthreads();

    const size_t lbase0 = (size_t)(0 * 256 + wg) * 32768;   // floats
    const size_t lbase1 = (size_t)(1 * 256 + wg) * 32768;

    #pragma unroll 1
    for (int t = 0; t < T_STEPS; ++t) {
        // ================= Layer 0: g0 = x@Wx0 + h0@Wh0 + b0 =================
        #pragma unroll 1
        for (int sb = 0; sb < 8; ++sb) {
            const int cgsb = cg * 8 + sb;
            const size_t sbase = lbase0 + (size_t)(wid * 8 + sb) * 256 + lane * 4;
            f32x4 cold, hold;
            if (t > 0) {
                cold = *(const f32x4*)(cws + sbase);
                hold = *(const f32x4*)(hws + sbase);
            } else {
                f32x4 zz = {0.f, 0.f, 0.f, 0.f}; cold = zz; hold = zz;
            }
            f32x4 acc[4];
            { f32x4 zz = {0.f, 0.f, 0.f, 0.f};
              acc[0] = zz; acc[1] = zz; acc[2] = zz; acc[3] = zz; }

            gemm_acc<2>((const char*)xs,  Wx0p, acc, arow * 128,  asw, lq16, laneoff, cgsb);
            gemm_acc<16>((const char*)h0s, Wh0p, acc, arow * 1024, asw, lq16, laneoff, cgsb);

            const int jcol = cg * 128 + sb * 16 + l15;
            float bia[4];
            #pragma unroll
            for (int g = 0; g < 4; ++g) bia[g] = b0v[g * 512 + jcol];

            f32x4 cnew, hnew;
            #pragma unroll
            for (int r = 0; r < 4; ++r) {
                const int row = rg * 16 + lq * 4 + r;
                const float flg = flags[row];
                float gi = acc[0][r] + bia[0];
                float gf = acc[1][r] + bia[1];
                float gg = acc[2][r] + bia[2];
                float go = acc[3][r] + bia[3];
                float cn = fast_sig(gf) * cold[r] + fast_sig(gi) * fast_tanh(gg);
                float hn = fast_sig(go) * fast_tanh(cn);
                cnew[r] = flg * cn + (1.f - flg) * cold[r];
                hnew[r] = flg * hn + (1.f - flg) * hold[r];
            }
            *(f32x4*)(cws + sbase) = cnew;
            *(f32x4*)(hws + sbase) = hnew;
        }
        __syncthreads();   // L0 done: hws complete, everyone done reading h0s/xs

        // fill h0s (bf16, swizzled) from hws, coalesced f32x4 reads
        for (int i4 = tid; i4 < BW * HID / 4; i4 += 1024) {
            f32x4 v = *(const f32x4*)(hws + lbase0 + (size_t)i4 * 4);
            int lane2 = i4 & 63, sb2 = (i4 >> 6) & 7, wid2 = i4 >> 9;
            int colb = (wid2 & 3) * 128 + sb2 * 16 + (lane2 & 15);
            int rowb = (wid2 >> 2) * 16 + (lane2 >> 4) * 4;
            #pragma unroll
            for (int r = 0; r < 4; ++r) {
                int row = rowb + r;
                int byte = row * 1024 + ((2 * colb) ^ ((row & 7) << 4));
                *(__hip_bfloat16*)((char*)h0s + byte) = __float2bfloat16(v[r]);
            }
        }
        __syncthreads();   // new h0s visible

        // ===== Layer 1: g1 = flag*Wx1[0] + h0_new@Wx1[1:] + h1@Wh1 + b1 =====
        #pragma unroll 1
        for (int sb = 0; sb < 8; ++sb) {
            const int cgsb = cg * 8 + sb;
            const size_t sbase = lbase1 + (size_t)(wid * 8 + sb) * 256 + lane * 4;
            f32x4 cold, hold;
            if (t > 0) {
                cold = *(const f32x4*)(cws + sbase);
                hold = *(const f32x4*)(hws + sbase);
            } else {
                f32x4 zz = {0.f, 0.f, 0.f, 0.f}; cold = zz; hold = zz;
            }
            f32x4 acc[4];
            { f32x4 zz = {0.f, 0.f, 0.f, 0.f};
              acc[0] = zz; acc[1] = zz; acc[2] = zz; acc[3] = zz; }

            gemm_acc<16>((const char*)h0s, Wx1hp, acc, arow * 1024, asw, lq16, laneoff, cgsb);
            gemm_acc<16>((const char*)h1s, Wh1p,  acc, arow * 1024, asw, lq16, laneoff, cgsb);

            const int jcol = cg * 128 + sb * 16 + l15;
            float bia[4], w10[4];
            #pragma unroll
            for (int g = 0; g < 4; ++g) {
                bia[g] = b1v[g * 512 + jcol];
                w10[g] = Wx1[g * 512 + jcol];   // Wx1 row 0 (flag weights)
            }
            f32x4 cnew, hnew;
            #pragma unroll
            for (int r = 0; r < 4; ++r) {
                const int row = rg * 16 + lq * 4 + r;
                const float flg = flags[row];
                float gi = acc[0][r] + bia[0] + flg * w10[0];
                float gf = acc[1][r] + bia[1] + flg * w10[1];
                float gg = acc[2][r] + bia[2] + flg * w10[2];
                float go = acc[3][r] + bia[3] + flg * w10[3];
                float cn = fast_sig(gf) * cold[r] + fast_sig(gi) * fast_tanh(gg);
                float hn = fast_sig(go) * fast_tanh(cn);
                cnew[r] = flg * cn + (1.f - flg) * cold[r];
                hnew[r] = flg * hn + (1.f - flg) * hold[r];
            }
            *(f32x4*)(cws + sbase) = cnew;
            *(f32x4*)(hws + sbase) = hnew;
        }
        __syncthreads();   // L1 done

        // fill h1s from hws; stage x(t+1) in the same phase
        for (int i4 = tid; i4 < BW * HID / 4; i4 += 1024) {
            f32x4 v = *(const f32x4*)(hws + lbase1 + (size_t)i4 * 4);
            int lane2 = i4 & 63, sb2 = (i4 >> 6) & 7, wid2 = i4 >> 9;
            int colb = (wid2 & 3) * 128 + sb2 * 16 + (lane2 & 15);
            int rowb = (wid2 >> 2) * 16 + (lane2 >> 4) * 4;
            #pragma unroll
            for (int r = 0; r < 4; ++r) {
                int row = rowb + r;
                int byte = row * 1024 + ((2 * colb) ^ ((row & 7) << 4));
                *(__hip_bfloat16*)((char*)h1s + byte) = __float2bfloat16(v[r]);
            }
        }
        if (t + 1 < T_STEPS) {
            for (int i = tid; i < BW * IN_F; i += 1024) {
                int row = i >> 6, k = i & 63;
                float v = x[(bbase + row) * (T_STEPS * IN_F) + (t + 1) * IN_F + k];
                int byte = row * 128 + ((2 * k) ^ ((row & 7) << 4));
                *(__hip_bfloat16*)((char*)xs + byte) = __float2bfloat16(v);
            }
            if (tid < BW) flags[tid] = x[(bbase + tid) * (T_STEPS * IN_F) + (t + 1) * IN_F];
        }
        __syncthreads();   // h1s/xs/flags ready for next step
    }

    // ---- final linear: out = h1 @ Wlin + blin  (64x512 @ 512x19) ----
    for (int task = tid; task < BW * OUT_F; task += 1024) {
        int o   = task >> 6;     // 0..18, wave-uniform
        int row = task & 63;
        float s = blin[o];
        const float* wl = Wlin + o;
        for (int k = 0; k < HID; ++k) {
            int byte = row * 1024 + ((2 * k) ^ ((row & 7) << 4));
            float hv = __bfloat162float(*(const __hip_bfloat16*)((const char*)h1s + byte));
            s += hv * wl[k * OUT_F];
        }
        out[(bbase + row) * OUT_F + o] = s;
    }
}

extern "C" void kernel_launch(void* const* d_in, const int* in_sizes, int n_in,
                              void* d_out, int out_size, void* d_ws, size_t ws_size,
                              hipStream_t stream) {
    const float* x    = (const float*)d_in[0];
    const float* Wx0  = (const float*)d_in[1];
    const float* Wh0  = (const float*)d_in[2];
    const float* b0   = (const float*)d_in[3];
    const float* Wx1  = (const float*)d_in[4];
    const float* Wh1  = (const float*)d_in[5];
    const float* b1   = (const float*)d_in[6];
    const float* Wlin = (const float*)d_in[7];
    const float* blin = (const float*)d_in[8];

    // workspace carve (bytes)
    const size_t offWx0p  = 0;                       // 2048*64*2   = 262144
    const size_t offWh0p  = 262144;                  // 2048*512*2  = 2097152
    const size_t offWx1hp = 2359296;
    const size_t offWh1p  = 4456448;
    const size_t offC     = 6553600;                 // 2*256*32768*4 = 67108864
    const size_t offH     = 73662464;                // 67108864
    const size_t needed   = 140771328;
    if (ws_size < needed) return;

    char* w = (char*)d_ws;
    __hip_bfloat16* Wx0p  = (__hip_bfloat16*)(w + offWx0p);
    __hip_bfloat16* Wh0p  = (__hip_bfloat16*)(w + offWh0p);
    __hip_bfloat16* Wx1hp = (__hip_bfloat16*)(w + offWx1hp);
    __hip_bfloat16* Wh1p  = (__hip_bfloat16*)(w + offWh1p);
    float* cws = (float*)(w + offC);
    float* hws = (float*)(w + offH);

    dim3 blk(256);
    wprep_kernel<<<(2048 * 64 + 255) / 256, blk, 0, stream>>>(Wx0, Wx0p, 1, 0);
    wprep_kernel<<<(2048 * 512 + 255) / 256, blk, 0, stream>>>(Wh0, Wh0p, 4, 0);
    wprep_kernel<<<(2048 * 512 + 255) / 256, blk, 0, stream>>>(Wx1, Wx1hp, 4, 1);  // skip flag row
    wprep_kernel<<<(2048 * 512 + 255) / 256, blk, 0, stream>>>(Wh1, Wh1p, 4, 0);

    lstm_main<<<256, 1024, 0, stream>>>(x, b0, Wx1, b1, Wlin, blin,
                                        Wx0p, Wh0p, Wx1hp, Wh1p, cws, hws, (float*)d_out);
}

// Round 5
// 9225.573 us; speedup vs baseline: 1.2877x; 1.2877x over previous
//
#include <hip/hip_runtime.h>
#include <hip/hip_bf16.h>

// SSNet: 2-layer flag-gated LSTM, persistent-tile MFMA implementation.
// B=16384, T=32, IN=64, H=512, OUT=19.
// R5: wave tile 32 rows x 64 gate-cols (2 MFMA rows per B-load, halved B
// load count, L1 pair-sharing); nontemporal state streams (protect L2
// weight residency); refill phases removed (packed-bf16 h_new in regs,
// direct LDS write post-barrier).

#define T_STEPS 32
#define IN_F    64
#define HID     512
#define OUT_F   19
#define BW      64   // batch rows per WG

typedef short bf16x8 __attribute__((ext_vector_type(8)));   // 8 bf16 = 4 VGPRs
typedef float f32x4  __attribute__((ext_vector_type(4)));

__device__ __forceinline__ float fast_sig(float x) {
    return __builtin_amdgcn_rcpf(1.0f + __expf(-x));
}
__device__ __forceinline__ float fast_tanh(float x) {
    return 1.0f - 2.0f * __builtin_amdgcn_rcpf(1.0f + __expf(2.0f * x));
}
__device__ __forceinline__ unsigned pack2(float a, float b) {
    return ((unsigned)__bfloat16_as_ushort(__float2bfloat16(b)) << 16)
         |  (unsigned)__bfloat16_as_ushort(__float2bfloat16(a));
}

// Packed B layout, per 16-col block cb of the 2048 gate-cols:
//   dst[cb*(K*16) + kc*512 + l15*32 + lq*8 + e] = W[kc*32+lq*8+e + rowOff][cb*16+l15]
__global__ void wprep_kernel(const float* __restrict__ src,
                             __hip_bfloat16* __restrict__ dst,
                             int kcBits, int rowOff) {
    int idx = blockIdx.x * 256 + threadIdx.x;
    int total = 2048 << (kcBits + 5);
    if (idx >= total) return;
    int e   = idx & 7;
    int lq  = (idx >> 3) & 3;
    int l15 = (idx >> 5) & 15;
    int kc  = (idx >> 9) & ((1 << kcBits) - 1);
    int cb  = idx >> (9 + kcBits);
    int k   = kc * 32 + lq * 8 + e + rowOff;
    int col = cb * 16 + l15;
    dst[idx] = __float2bfloat16(src[(size_t)k * 2048 + col]);
}

// acc[rt][g] += A(rows rt*16.., from LDS) x B(packed global)
template<int KC, int RS>
__device__ __forceinline__ void gemm2(const char* __restrict__ alds,
                                      const __hip_bfloat16* __restrict__ Bp,
                                      f32x4 acc[2][4],
                                      int a0, int asw, int lq16,
                                      int laneoff, int cgsb) {
    const __hip_bfloat16* bp0 = Bp + (size_t)(0 * 32 + cgsb) * (KC * 512) + laneoff;
    const __hip_bfloat16* bp1 = Bp + (size_t)(1 * 32 + cgsb) * (KC * 512) + laneoff;
    const __hip_bfloat16* bp2 = Bp + (size_t)(2 * 32 + cgsb) * (KC * 512) + laneoff;
    const __hip_bfloat16* bp3 = Bp + (size_t)(3 * 32 + cgsb) * (KC * 512) + laneoff;
    #pragma unroll 2
    for (int kc = 0; kc < KC; ++kc) {
        const int ab = (kc * 64 + lq16) ^ asw;
        bf16x8 b0 = *(const bf16x8*)(bp0 + kc * 512);
        bf16x8 b1 = *(const bf16x8*)(bp1 + kc * 512);
        bf16x8 b2 = *(const bf16x8*)(bp2 + kc * 512);
        bf16x8 b3 = *(const bf16x8*)(bp3 + kc * 512);
        bf16x8 x0 = *(const bf16x8*)(alds + a0 + ab);
        bf16x8 x1 = *(const bf16x8*)(alds + a0 + 16 * RS + ab);
        acc[0][0] = __builtin_amdgcn_mfma_f32_16x16x32_bf16(x0, b0, acc[0][0], 0, 0, 0);
        acc[1][0] = __builtin_amdgcn_mfma_f32_16x16x32_bf16(x1, b0, acc[1][0], 0, 0, 0);
        acc[0][1] = __builtin_amdgcn_mfma_f32_16x16x32_bf16(x0, b1, acc[0][1], 0, 0, 0);
        acc[1][1] = __builtin_amdgcn_mfma_f32_16x16x32_bf16(x1, b1, acc[1][1], 0, 0, 0);
        acc[0][2] = __builtin_amdgcn_mfma_f32_16x16x32_bf16(x0, b2, acc[0][2], 0, 0, 0);
        acc[1][2] = __builtin_amdgcn_mfma_f32_16x16x32_bf16(x1, b2, acc[1][2], 0, 0, 0);
        acc[0][3] = __builtin_amdgcn_mfma_f32_16x16x32_bf16(x0, b3, acc[0][3], 0, 0, 0);
        acc[1][3] = __builtin_amdgcn_mfma_f32_16x16x32_bf16(x1, b3, acc[1][3], 0, 0, 0);
    }
}

__global__ __launch_bounds__(1024, 4)
void lstm_main(const float* __restrict__ x,
               const float* __restrict__ b0v,
               const float* __restrict__ Wx1,     // row 0 = flag weights (f32)
               const float* __restrict__ b1v,
               const float* __restrict__ Wlin,
               const float* __restrict__ blin,
               const __hip_bfloat16* __restrict__ Wx0p,
               const __hip_bfloat16* __restrict__ Wh0p,
               const __hip_bfloat16* __restrict__ Wx1hp,
               const __hip_bfloat16* __restrict__ Wh1p,
               float* __restrict__ cws,
               float* __restrict__ hws,
               float* __restrict__ out)
{
    // LDS h tiles: row-major bf16, row stride 1024B, XOR-swizzle (row&7)<<4
    __shared__ __align__(16) __hip_bfloat16 h0s[BW * HID];   // 64 KB
    __shared__ __align__(16) __hip_bfloat16 h1s[BW * HID];   // 64 KB
    __shared__ __align__(16) __hip_bfloat16 xs[BW * IN_F];   // 8 KB, row stride 128B
    __shared__ float flags[BW];

    const int tid  = threadIdx.x;
    const int lane = tid & 63;
    const int wid  = tid >> 6;      // 0..15
    const int rg   = wid & 1;       // 2 row-groups of 32 rows
    const int cg   = wid >> 1;      // 8 col-groups of 64 gate-cols (per gate)
    const int l15  = lane & 15;
    const int lq   = lane >> 4;
    const int lq16 = lq * 16;
    const int laneoff = l15 * 32 + lq * 8;
    const int rbase = rg * 32;
    const int asw  = (l15 & 7) << 4;        // rbase % 8 == 0
    const int a0h  = (rbase + l15) * 1024;  // h-tile A byte base (rt=0)
    const int a0x  = (rbase + l15) * 128;   // x-tile A byte base
    const int wg   = blockIdx.x;
    const size_t bbase = (size_t)wg * BW;

    // zero h LDS
    {
        int4 z; z.x = z.y = z.z = z.w = 0;
        int4* p0 = (int4*)h0s; int4* p1 = (int4*)h1s;
        for (int i = tid; i < BW * HID * 2 / 16; i += 1024) { p0[i] = z; p1[i] = z; }
    }
    // stage x(0) + flags
    for (int i = tid; i < BW * IN_F; i += 1024) {
        int row = i >> 6, k = i & 63;
        float v = __builtin_nontemporal_load(&x[(bbase + row) * (T_STEPS * IN_F) + k]);
        int byte = row * 128 + ((2 * k) ^ ((row & 7) << 4));
        *(__hip_bfloat16*)((char*)xs + byte) = __float2bfloat16(v);
    }
    if (tid < BW) flags[tid] = x[(bbase + tid) * (T_STEPS * IN_F)];
    __syncthreads();

    const size_t wsWG0 = (size_t)(0 * 256 + wg) * 32768;   // floats
    const size_t wsWG1 = (size_t)(1 * 256 + wg) * 32768;

    #pragma unroll 1
    for (int t = 0; t < T_STEPS; ++t) {
        // flag registers for this step (rows fixed per thread)
        float flg[2][4];
        #pragma unroll
        for (int rt = 0; rt < 2; ++rt)
            #pragma unroll
            for (int r = 0; r < 4; ++r)
                flg[rt][r] = flags[rbase + rt * 16 + lq * 4 + r];

        unsigned hnr[4][2][2];   // packed bf16 h_new [sb][rt][pair]

        // ================= Layer 0: g0 = x@Wx0 + h0@Wh0 + b0 =================
        #pragma unroll
        for (int sb = 0; sb < 4; ++sb) {
            const int cgsb = cg * 4 + sb;
            const size_t sbase = wsWG0 + (size_t)((wid * 4 + sb) * 2) * 256 + lane * 4;
            f32x4 cold[2], hold[2];
            if (t > 0) {
                cold[0] = __builtin_nontemporal_load((const f32x4*)(cws + sbase));
                cold[1] = __builtin_nontemporal_load((const f32x4*)(cws + sbase + 256));
                hold[0] = __builtin_nontemporal_load((const f32x4*)(hws + sbase));
                hold[1] = __builtin_nontemporal_load((const f32x4*)(hws + sbase + 256));
            } else {
                f32x4 zz = {0.f, 0.f, 0.f, 0.f};
                cold[0] = zz; cold[1] = zz; hold[0] = zz; hold[1] = zz;
            }
            f32x4 acc[2][4];
            { f32x4 zz = {0.f, 0.f, 0.f, 0.f};
              #pragma unroll
              for (int rt = 0; rt < 2; ++rt)
                  #pragma unroll
                  for (int g = 0; g < 4; ++g) acc[rt][g] = zz; }

            gemm2<2, 128>((const char*)xs,  Wx0p, acc, a0x, asw, lq16, laneoff, cgsb);
            gemm2<16, 1024>((const char*)h0s, Wh0p, acc, a0h, asw, lq16, laneoff, cgsb);

            const int jcol = cg * 64 + sb * 16 + l15;
            float bia[4];
            #pragma unroll
            for (int g = 0; g < 4; ++g) bia[g] = b0v[g * 512 + jcol];

            #pragma unroll
            for (int rt = 0; rt < 2; ++rt) {
                f32x4 cnew, hnew;
                #pragma unroll
                for (int r = 0; r < 4; ++r) {
                    const float f = flg[rt][r];
                    float gi = acc[rt][0][r] + bia[0];
                    float gf = acc[rt][1][r] + bia[1];
                    float gg = acc[rt][2][r] + bia[2];
                    float go = acc[rt][3][r] + bia[3];
                    float cn = fast_sig(gf) * cold[rt][r] + fast_sig(gi) * fast_tanh(gg);
                    float hn = fast_sig(go) * fast_tanh(cn);
                    cnew[r] = f * cn + (1.f - f) * cold[rt][r];
                    hnew[r] = f * hn + (1.f - f) * hold[rt][r];
                }
                __builtin_nontemporal_store(cnew, (f32x4*)(cws + sbase + rt * 256));
                __builtin_nontemporal_store(hnew, (f32x4*)(hws + sbase + rt * 256));
                hnr[sb][rt][0] = pack2(hnew[0], hnew[1]);
                hnr[sb][rt][1] = pack2(hnew[2], hnew[3]);
            }
        }
        __syncthreads();   // all waves done reading h0s/xs
        // write new h0 -> LDS directly from registers
        #pragma unroll
        for (int sb = 0; sb < 4; ++sb) {
            const int col2 = 2 * (cg * 64 + sb * 16 + l15);
            #pragma unroll
            for (int rt = 0; rt < 2; ++rt)
                #pragma unroll
                for (int p = 0; p < 2; ++p) {
                    unsigned u = hnr[sb][rt][p];
                    int row = rbase + rt * 16 + lq * 4 + 2 * p;
                    *(unsigned short*)((char*)h0s + row * 1024 + (col2 ^ ((row & 7) << 4))) = (unsigned short)u;
                    ++row;
                    *(unsigned short*)((char*)h0s + row * 1024 + (col2 ^ ((row & 7) << 4))) = (unsigned short)(u >> 16);
                }
        }
        __syncthreads();   // new h0s visible

        // ===== Layer 1: g1 = flag*Wx1[0] + h0_new@Wx1[1:] + h1@Wh1 + b1 =====
        #pragma unroll
        for (int sb = 0; sb < 4; ++sb) {
            const int cgsb = cg * 4 + sb;
            const size_t sbase = wsWG1 + (size_t)((wid * 4 + sb) * 2) * 256 + lane * 4;
            f32x4 cold[2], hold[2];
            if (t > 0) {
                cold[0] = __builtin_nontemporal_load((const f32x4*)(cws + sbase));
                cold[1] = __builtin_nontemporal_load((const f32x4*)(cws + sbase + 256));
                hold[0] = __builtin_nontemporal_load((const f32x4*)(hws + sbase));
                hold[1] = __builtin_nontemporal_load((const f32x4*)(hws + sbase + 256));
            } else {
                f32x4 zz = {0.f, 0.f, 0.f, 0.f};
                cold[0] = zz; cold[1] = zz; hold[0] = zz; hold[1] = zz;
            }
            f32x4 acc[2][4];
            { f32x4 zz = {0.f, 0.f, 0.f, 0.f};
              #pragma unroll
              for (int rt = 0; rt < 2; ++rt)
                  #pragma unroll
                  for (int g = 0; g < 4; ++g) acc[rt][g] = zz; }

            gemm2<16, 1024>((const char*)h0s, Wx1hp, acc, a0h, asw, lq16, laneoff, cgsb);
            gemm2<16, 1024>((const char*)h1s, Wh1p,  acc, a0h, asw, lq16, laneoff, cgsb);

            const int jcol = cg * 64 + sb * 16 + l15;
            float bia[4], w10[4];
            #pragma unroll
            for (int g = 0; g < 4; ++g) {
                bia[g] = b1v[g * 512 + jcol];
                w10[g] = Wx1[g * 512 + jcol];   // Wx1 row 0 (flag weights)
            }
            #pragma unroll
            for (int rt = 0; rt < 2; ++rt) {
                f32x4 cnew, hnew;
                #pragma unroll
                for (int r = 0; r < 4; ++r) {
                    const float f = flg[rt][r];
                    float gi = acc[rt][0][r] + bia[0] + f * w10[0];
                    float gf = acc[rt][1][r] + bia[1] + f * w10[1];
                    float gg = acc[rt][2][r] + bia[2] + f * w10[2];
                    float go = acc[rt][3][r] + bia[3] + f * w10[3];
                    float cn = fast_sig(gf) * cold[rt][r] + fast_sig(gi) * fast_tanh(gg);
                    float hn = fast_sig(go) * fast_tanh(cn);
                    cnew[r] = f * cn + (1.f - f) * cold[rt][r];
                    hnew[r] = f * hn + (1.f - f) * hold[rt][r];
                }
                __builtin_nontemporal_store(cnew, (f32x4*)(cws + sbase + rt * 256));
                __builtin_nontemporal_store(hnew, (f32x4*)(hws + sbase + rt * 256));
                hnr[sb][rt][0] = pack2(hnew[0], hnew[1]);
                hnr[sb][rt][1] = pack2(hnew[2], hnew[3]);
            }
        }
        __syncthreads();   // all waves done reading h0s/h1s

        // write new h1 -> LDS; stage x(t+1) + flags in the same phase
        #pragma unroll
        for (int sb = 0; sb < 4; ++sb) {
            const int col2 = 2 * (cg * 64 + sb * 16 + l15);
            #pragma unroll
            for (int rt = 0; rt < 2; ++rt)
                #pragma unroll
                for (int p = 0; p < 2; ++p) {
                    unsigned u = hnr[sb][rt][p];
                    int row = rbase + rt * 16 + lq * 4 + 2 * p;
                    *(unsigned short*)((char*)h1s + row * 1024 + (col2 ^ ((row & 7) << 4))) = (unsigned short)u;
                    ++row;
                    *(unsigned short*)((char*)h1s + row * 1024 + (col2 ^ ((row & 7) << 4))) = (unsigned short)(u >> 16);
                }
        }
        if (t + 1 < T_STEPS) {
            for (int i = tid; i < BW * IN_F; i += 1024) {
                int row = i >> 6, k = i & 63;
                float v = __builtin_nontemporal_load(&x[(bbase + row) * (T_STEPS * IN_F) + (t + 1) * IN_F + k]);
                int byte = row * 128 + ((2 * k) ^ ((row & 7) << 4));
                *(__hip_bfloat16*)((char*)xs + byte) = __float2bfloat16(v);
            }
            if (tid < BW) flags[tid] = x[(bbase + tid) * (T_STEPS * IN_F) + (t + 1) * IN_F];
        }
        __syncthreads();   // h1s/xs/flags ready for next step
    }

    // ---- final linear: out = h1 @ Wlin + blin  (64x512 @ 512x19) ----
    for (int task = tid; task < BW * OUT_F; task += 1024) {
        int o   = task >> 6;     // 0..18, wave-uniform
        int row = task & 63;
        float s = blin[o];
        const float* wl = Wlin + o;
        for (int k = 0; k < HID; ++k) {
            int byte = row * 1024 + ((2 * k) ^ ((row & 7) << 4));
            float hv = __bfloat162float(*(const __hip_bfloat16*)((const char*)h1s + byte));
            s += hv * wl[k * OUT_F];
        }
        out[(bbase + row) * OUT_F + o] = s;
    }
}

extern "C" void kernel_launch(void* const* d_in, const int* in_sizes, int n_in,
                              void* d_out, int out_size, void* d_ws, size_t ws_size,
                              hipStream_t stream) {
    const float* x    = (const float*)d_in[0];
    const float* Wx0  = (const float*)d_in[1];
    const float* Wh0  = (const float*)d_in[2];
    const float* b0   = (const float*)d_in[3];
    const float* Wx1  = (const float*)d_in[4];
    const float* Wh1  = (const float*)d_in[5];
    const float* b1   = (const float*)d_in[6];
    const float* Wlin = (const float*)d_in[7];
    const float* blin = (const float*)d_in[8];

    // workspace carve (bytes)
    const size_t offWx0p  = 0;                       // 2048*64*2   = 262144
    const size_t offWh0p  = 262144;                  // 2048*512*2  = 2097152
    const size_t offWx1hp = 2359296;
    const size_t offWh1p  = 4456448;
    const size_t offC     = 6553600;                 // 2*256*32768*4 = 67108864
    const size_t offH     = 73662464;                // 67108864
    const size_t needed   = 140771328;
    if (ws_size < needed) return;

    char* w = (char*)d_ws;
    __hip_bfloat16* Wx0p  = (__hip_bfloat16*)(w + offWx0p);
    __hip_bfloat16* Wh0p  = (__hip_bfloat16*)(w + offWh0p);
    __hip_bfloat16* Wx1hp = (__hip_bfloat16*)(w + offWx1hp);
    __hip_bfloat16* Wh1p  = (__hip_bfloat16*)(w + offWh1p);
    float* cws = (float*)(w + offC);
    float* hws = (float*)(w + offH);

    dim3 blk(256);
    wprep_kernel<<<(2048 * 64 + 255) / 256, blk, 0, stream>>>(Wx0, Wx0p, 1, 0);
    wprep_kernel<<<(2048 * 512 + 255) / 256, blk, 0, stream>>>(Wh0, Wh0p, 4, 0);
    wprep_kernel<<<(2048 * 512 + 255) / 256, blk, 0, stream>>>(Wx1, Wx1hp, 4, 1);  // skip flag row
    wprep_kernel<<<(2048 * 512 + 255) / 256, blk, 0, stream>>>(Wh1, Wh1p, 4, 0);

    lstm_main<<<256, 1024, 0, stream>>>(x, b0, Wx1, b1, Wlin, blin,
                                        Wx0p, Wh0p, Wx1hp, Wh1p, cws, hws, (float*)d_out);
}

// Round 6
// 8252.993 us; speedup vs baseline: 1.4394x; 1.1178x over previous
//
#include <hip/hip_runtime.h>
#include <hip/hip_bf16.h>

// SSNet: 2-layer flag-gated LSTM, persistent-tile MFMA implementation.
// B=16384, T=32, IN=64, H=512, OUT=19.
// R6: explicit depth-2 B-load register pipeline (merged per-layer streams,
// loads issued 1.5 chunks ahead of use); light barriers (lgkmcnt-only +
// raw s_barrier) so nt HBM state stores don't serialize phase boundaries.

#define T_STEPS 32
#define IN_F    64
#define HID     512
#define OUT_F   19
#define BW      64   // batch rows per WG

typedef short bf16x8 __attribute__((ext_vector_type(8)));   // 8 bf16 = 4 VGPRs
typedef float f32x4  __attribute__((ext_vector_type(4)));

__device__ __forceinline__ float fast_sig(float x) {
    return __builtin_amdgcn_rcpf(1.0f + __expf(-x));
}
__device__ __forceinline__ float fast_tanh(float x) {
    return 1.0f - 2.0f * __builtin_amdgcn_rcpf(1.0f + __expf(2.0f * x));
}
__device__ __forceinline__ unsigned pack2(float a, float b) {
    return ((unsigned)__bfloat16_as_ushort(__float2bfloat16(b)) << 16)
         |  (unsigned)__bfloat16_as_ushort(__float2bfloat16(a));
}

// Light barrier: LDS hazards only (don't drain vmcnt -> nt HBM stores fly on).
#define LBAR() do { \
    asm volatile("s_waitcnt lgkmcnt(0)" ::: "memory"); \
    __builtin_amdgcn_sched_barrier(0); \
    __builtin_amdgcn_s_barrier(); \
    __builtin_amdgcn_sched_barrier(0); \
} while (0)

#define MFMA8(x0, x1, q0, q1, q2, q3) do { \
    acc[0][0] = __builtin_amdgcn_mfma_f32_16x16x32_bf16(x0, q0, acc[0][0], 0, 0, 0); \
    acc[1][0] = __builtin_amdgcn_mfma_f32_16x16x32_bf16(x1, q0, acc[1][0], 0, 0, 0); \
    acc[0][1] = __builtin_amdgcn_mfma_f32_16x16x32_bf16(x0, q1, acc[0][1], 0, 0, 0); \
    acc[1][1] = __builtin_amdgcn_mfma_f32_16x16x32_bf16(x1, q1, acc[1][1], 0, 0, 0); \
    acc[0][2] = __builtin_amdgcn_mfma_f32_16x16x32_bf16(x0, q2, acc[0][2], 0, 0, 0); \
    acc[1][2] = __builtin_amdgcn_mfma_f32_16x16x32_bf16(x1, q2, acc[1][2], 0, 0, 0); \
    acc[0][3] = __builtin_amdgcn_mfma_f32_16x16x32_bf16(x0, q3, acc[0][3], 0, 0, 0); \
    acc[1][3] = __builtin_amdgcn_mfma_f32_16x16x32_bf16(x1, q3, acc[1][3], 0, 0, 0); \
} while (0)

// Packed B layout, per 16-col block cb of the 2048 gate-cols:
//   dst[cb*(K*16) + kc*512 + l15*32 + lq*8 + e] = W[kc*32+lq*8+e + rowOff][cb*16+l15]
__global__ void wprep_kernel(const float* __restrict__ src,
                             __hip_bfloat16* __restrict__ dst,
                             int kcBits, int rowOff) {
    int idx = blockIdx.x * 256 + threadIdx.x;
    int total = 2048 << (kcBits + 5);
    if (idx >= total) return;
    int e   = idx & 7;
    int lq  = (idx >> 3) & 3;
    int l15 = (idx >> 5) & 15;
    int kc  = (idx >> 9) & ((1 << kcBits) - 1);
    int cb  = idx >> (9 + kcBits);
    int k   = kc * 32 + lq * 8 + e + rowOff;
    int col = cb * 16 + l15;
    dst[idx] = __float2bfloat16(src[(size_t)k * 2048 + col]);
}

__global__ __launch_bounds__(1024, 4)
void lstm_main(const float* __restrict__ x,
               const float* __restrict__ b0v,
               const float* __restrict__ Wx1,     // row 0 = flag weights (f32)
               const float* __restrict__ b1v,
               const float* __restrict__ Wlin,
               const float* __restrict__ blin,
               const __hip_bfloat16* __restrict__ Wx0p,
               const __hip_bfloat16* __restrict__ Wh0p,
               const __hip_bfloat16* __restrict__ Wx1hp,
               const __hip_bfloat16* __restrict__ Wh1p,
               float* __restrict__ cws,
               float* __restrict__ hws,
               float* __restrict__ out)
{
    // LDS h tiles: row-major bf16, row stride 1024B, XOR-swizzle (row&7)<<4
    __shared__ __align__(16) __hip_bfloat16 h0s[BW * HID];   // 64 KB
    __shared__ __align__(16) __hip_bfloat16 h1s[BW * HID];   // 64 KB
    __shared__ __align__(16) __hip_bfloat16 xs[BW * IN_F];   // 8 KB, row stride 128B
    __shared__ float flags[BW];

    const int tid  = threadIdx.x;
    const int lane = tid & 63;
    const int wid  = tid >> 6;      // 0..15
    const int rg   = wid & 1;       // 2 row-groups of 32 rows
    const int cg   = wid >> 1;      // 8 col-groups of 64 gate-cols (per gate)
    const int l15  = lane & 15;
    const int lq   = lane >> 4;
    const int lq16 = lq * 16;
    const int laneoff = l15 * 32 + lq * 8;
    const int rbase = rg * 32;
    const int asw  = (l15 & 7) << 4;        // rbase % 8 == 0, +16 keeps (row&7)
    const int a0h  = (rbase + l15) * 1024;  // h-tile A byte base (rt=0)
    const int a0x  = (rbase + l15) * 128;   // x-tile A byte base
    const int wg   = blockIdx.x;
    const size_t bbase = (size_t)wg * BW;
    const char* xsC = (const char*)xs;
    const char* h0C = (const char*)h0s;
    const char* h1C = (const char*)h1s;

    // zero h LDS
    {
        int4 z; z.x = z.y = z.z = z.w = 0;
        int4* p0 = (int4*)h0s; int4* p1 = (int4*)h1s;
        for (int i = tid; i < BW * HID * 2 / 16; i += 1024) { p0[i] = z; p1[i] = z; }
    }
    // stage x(0) + flags
    for (int i = tid; i < BW * IN_F; i += 1024) {
        int row = i >> 6, k = i & 63;
        float v = __builtin_nontemporal_load(&x[(bbase + row) * (T_STEPS * IN_F) + k]);
        int byte = row * 128 + ((2 * k) ^ ((row & 7) << 4));
        *(__hip_bfloat16*)((char*)xs + byte) = __float2bfloat16(v);
    }
    if (tid < BW) flags[tid] = x[(bbase + tid) * (T_STEPS * IN_F)];
    LBAR();

    const size_t wsWG0 = (size_t)(0 * 256 + wg) * 32768;   // floats
    const size_t wsWG1 = (size_t)(1 * 256 + wg) * 32768;

    #pragma unroll 1
    for (int t = 0; t < T_STEPS; ++t) {
        unsigned hnr[4][2][2];   // packed bf16 h_new [sb][rt][pair]

        // ================= Layer 0: g0 = x@Wx0 + h0@Wh0 + b0 =================
        #pragma unroll 1
        for (int sb = 0; sb < 4; ++sb) {
            const int cgsb = cg * 4 + sb;
            const size_t sbase = wsWG0 + (size_t)((wid * 4 + sb) * 2) * 256 + lane * 4;
            f32x4 cold[2], hold[2];
            if (t > 0) {
                cold[0] = __builtin_nontemporal_load((const f32x4*)(cws + sbase));
                cold[1] = __builtin_nontemporal_load((const f32x4*)(cws + sbase + 256));
                hold[0] = __builtin_nontemporal_load((const f32x4*)(hws + sbase));
                hold[1] = __builtin_nontemporal_load((const f32x4*)(hws + sbase + 256));
            } else {
                f32x4 zz = {0.f, 0.f, 0.f, 0.f};
                cold[0] = zz; cold[1] = zz; hold[0] = zz; hold[1] = zz;
            }

            const __hip_bfloat16* Bx = Wx0p + (size_t)cgsb * 1024 + laneoff;  // +g*32768, +m*512
            const __hip_bfloat16* Bh = Wh0p + (size_t)cgsb * 8192 + laneoff;  // +g*262144, +(m-2)*512
            auto loadB = [&](int m, bf16x8& d0, bf16x8& d1, bf16x8& d2, bf16x8& d3) {
                if (m < 2) {
                    const __hip_bfloat16* p = Bx + m * 512;
                    d0 = *(const bf16x8*)(p);
                    d1 = *(const bf16x8*)(p + 32768);
                    d2 = *(const bf16x8*)(p + 65536);
                    d3 = *(const bf16x8*)(p + 98304);
                } else {
                    const __hip_bfloat16* p = Bh + (m - 2) * 512;
                    d0 = *(const bf16x8*)(p);
                    d1 = *(const bf16x8*)(p + 262144);
                    d2 = *(const bf16x8*)(p + 524288);
                    d3 = *(const bf16x8*)(p + 786432);
                }
            };
            auto loadA = [&](int m, bf16x8& x0, bf16x8& x1) {
                if (m < 2) {
                    int ab = a0x + ((m * 64 + lq16) ^ asw);
                    x0 = *(const bf16x8*)(xsC + ab);
                    x1 = *(const bf16x8*)(xsC + 16 * 128 + ab);
                } else {
                    int ab = a0h + (((m - 2) * 64 + lq16) ^ asw);
                    x0 = *(const bf16x8*)(h0C + ab);
                    x1 = *(const bf16x8*)(h0C + 16 * 1024 + ab);
                }
            };

            f32x4 acc[2][4];
            { f32x4 zz = {0.f, 0.f, 0.f, 0.f};
              #pragma unroll
              for (int rt = 0; rt < 2; ++rt)
                  #pragma unroll
                  for (int g = 0; g < 4; ++g) acc[rt][g] = zz; }

            bf16x8 pa0, pa1, pa2, pa3, pb0, pb1, pb2, pb3, x0, x1;
            loadB(0, pa0, pa1, pa2, pa3);
            #pragma unroll 1
            for (int m = 0; m < 18; m += 2) {
                loadB(m + 1, pb0, pb1, pb2, pb3);
                loadA(m, x0, x1);
                MFMA8(x0, x1, pa0, pa1, pa2, pa3);
                if (m + 2 < 18) loadB(m + 2, pa0, pa1, pa2, pa3);
                loadA(m + 1, x0, x1);
                MFMA8(x0, x1, pb0, pb1, pb2, pb3);
            }

            const int jcol = cg * 64 + sb * 16 + l15;
            float bia[4];
            #pragma unroll
            for (int g = 0; g < 4; ++g) bia[g] = b0v[g * 512 + jcol];

            #pragma unroll
            for (int rt = 0; rt < 2; ++rt) {
                f32x4 cnew, hnew;
                #pragma unroll
                for (int r = 0; r < 4; ++r) {
                    const float f = flags[rbase + rt * 16 + lq * 4 + r];
                    float gi = acc[rt][0][r] + bia[0];
                    float gf = acc[rt][1][r] + bia[1];
                    float gg = acc[rt][2][r] + bia[2];
                    float go = acc[rt][3][r] + bia[3];
                    float cn = fast_sig(gf) * cold[rt][r] + fast_sig(gi) * fast_tanh(gg);
                    float hn = fast_sig(go) * fast_tanh(cn);
                    cnew[r] = f * cn + (1.f - f) * cold[rt][r];
                    hnew[r] = f * hn + (1.f - f) * hold[rt][r];
                }
                __builtin_nontemporal_store(cnew, (f32x4*)(cws + sbase + rt * 256));
                __builtin_nontemporal_store(hnew, (f32x4*)(hws + sbase + rt * 256));
                hnr[sb][rt][0] = pack2(hnew[0], hnew[1]);
                hnr[sb][rt][1] = pack2(hnew[2], hnew[3]);
            }
        }
        LBAR();   // all waves done reading h0s/xs
        // write new h0 -> LDS directly from registers
        #pragma unroll
        for (int sb = 0; sb < 4; ++sb) {
            const int col2 = 2 * (cg * 64 + sb * 16 + l15);
            #pragma unroll
            for (int rt = 0; rt < 2; ++rt)
                #pragma unroll
                for (int p = 0; p < 2; ++p) {
                    unsigned u = hnr[sb][rt][p];
                    int row = rbase + rt * 16 + lq * 4 + 2 * p;
                    *(unsigned short*)((char*)h0s + row * 1024 + (col2 ^ ((row & 7) << 4))) = (unsigned short)u;
                    ++row;
                    *(unsigned short*)((char*)h0s + row * 1024 + (col2 ^ ((row & 7) << 4))) = (unsigned short)(u >> 16);
                }
        }
        LBAR();   // new h0s visible

        // ===== Layer 1: g1 = flag*Wx1[0] + h0_new@Wx1[1:] + h1@Wh1 + b1 =====
        #pragma unroll 1
        for (int sb = 0; sb < 4; ++sb) {
            const int cgsb = cg * 4 + sb;
            const size_t sbase = wsWG1 + (size_t)((wid * 4 + sb) * 2) * 256 + lane * 4;
            f32x4 cold[2], hold[2];
            if (t > 0) {
                cold[0] = __builtin_nontemporal_load((const f32x4*)(cws + sbase));
                cold[1] = __builtin_nontemporal_load((const f32x4*)(cws + sbase + 256));
                hold[0] = __builtin_nontemporal_load((const f32x4*)(hws + sbase));
                hold[1] = __builtin_nontemporal_load((const f32x4*)(hws + sbase + 256));
            } else {
                f32x4 zz = {0.f, 0.f, 0.f, 0.f};
                cold[0] = zz; cold[1] = zz; hold[0] = zz; hold[1] = zz;
            }

            const __hip_bfloat16* B1 = Wx1hp + (size_t)cgsb * 8192 + laneoff;  // +g*262144, +m*512
            const __hip_bfloat16* B2 = Wh1p  + (size_t)cgsb * 8192 + laneoff;  // +g*262144, +(m-16)*512
            auto loadB = [&](int m, bf16x8& d0, bf16x8& d1, bf16x8& d2, bf16x8& d3) {
                const __hip_bfloat16* p = (m < 16) ? (B1 + m * 512) : (B2 + (m - 16) * 512);
                d0 = *(const bf16x8*)(p);
                d1 = *(const bf16x8*)(p + 262144);
                d2 = *(const bf16x8*)(p + 524288);
                d3 = *(const bf16x8*)(p + 786432);
            };
            auto loadA = [&](int m, bf16x8& x0, bf16x8& x1) {
                const char* base = (m < 16) ? h0C : h1C;
                int ab = a0h + (((m & 15) * 64 + lq16) ^ asw);
                x0 = *(const bf16x8*)(base + ab);
                x1 = *(const bf16x8*)(base + 16 * 1024 + ab);
            };

            f32x4 acc[2][4];
            { f32x4 zz = {0.f, 0.f, 0.f, 0.f};
              #pragma unroll
              for (int rt = 0; rt < 2; ++rt)
                  #pragma unroll
                  for (int g = 0; g < 4; ++g) acc[rt][g] = zz; }

            bf16x8 pa0, pa1, pa2, pa3, pb0, pb1, pb2, pb3, x0, x1;
            loadB(0, pa0, pa1, pa2, pa3);
            #pragma unroll 1
            for (int m = 0; m < 32; m += 2) {
                loadB(m + 1, pb0, pb1, pb2, pb3);
                loadA(m, x0, x1);
                MFMA8(x0, x1, pa0, pa1, pa2, pa3);
                if (m + 2 < 32) loadB(m + 2, pa0, pa1, pa2, pa3);
                loadA(m + 1, x0, x1);
                MFMA8(x0, x1, pb0, pb1, pb2, pb3);
            }

            const int jcol = cg * 64 + sb * 16 + l15;
            float bia[4], w10[4];
            #pragma unroll
            for (int g = 0; g < 4; ++g) {
                bia[g] = b1v[g * 512 + jcol];
                w10[g] = Wx1[g * 512 + jcol];   // Wx1 row 0 (flag weights)
            }
            #pragma unroll
            for (int rt = 0; rt < 2; ++rt) {
                f32x4 cnew, hnew;
                #pragma unroll
                for (int r = 0; r < 4; ++r) {
                    const float f = flags[rbase + rt * 16 + lq * 4 + r];
                    float gi = acc[rt][0][r] + bia[0] + f * w10[0];
                    float gf = acc[rt][1][r] + bia[1] + f * w10[1];
                    float gg = acc[rt][2][r] + bia[2] + f * w10[2];
                    float go = acc[rt][3][r] + bia[3] + f * w10[3];
                    float cn = fast_sig(gf) * cold[rt][r] + fast_sig(gi) * fast_tanh(gg);
                    float hn = fast_sig(go) * fast_tanh(cn);
                    cnew[r] = f * cn + (1.f - f) * cold[rt][r];
                    hnew[r] = f * hn + (1.f - f) * hold[rt][r];
                }
                __builtin_nontemporal_store(cnew, (f32x4*)(cws + sbase + rt * 256));
                __builtin_nontemporal_store(hnew, (f32x4*)(hws + sbase + rt * 256));
                hnr[sb][rt][0] = pack2(hnew[0], hnew[1]);
                hnr[sb][rt][1] = pack2(hnew[2], hnew[3]);
            }
        }
        LBAR();   // all waves done reading h0s/h1s

        // write new h1 -> LDS; stage x(t+1) + flags in the same phase
        #pragma unroll
        for (int sb = 0; sb < 4; ++sb) {
            const int col2 = 2 * (cg * 64 + sb * 16 + l15);
            #pragma unroll
            for (int rt = 0; rt < 2; ++rt)
                #pragma unroll
                for (int p = 0; p < 2; ++p) {
                    unsigned u = hnr[sb][rt][p];
                    int row = rbase + rt * 16 + lq * 4 + 2 * p;
                    *(unsigned short*)((char*)h1s + row * 1024 + (col2 ^ ((row & 7) << 4))) = (unsigned short)u;
                    ++row;
                    *(unsigned short*)((char*)h1s + row * 1024 + (col2 ^ ((row & 7) << 4))) = (unsigned short)(u >> 16);
                }
        }
        if (t + 1 < T_STEPS) {
            for (int i = tid; i < BW * IN_F; i += 1024) {
                int row = i >> 6, k = i & 63;
                float v = __builtin_nontemporal_load(&x[(bbase + row) * (T_STEPS * IN_F) + (t + 1) * IN_F + k]);
                int byte = row * 128 + ((2 * k) ^ ((row & 7) << 4));
                *(__hip_bfloat16*)((char*)xs + byte) = __float2bfloat16(v);
            }
            if (tid < BW) flags[tid] = x[(bbase + tid) * (T_STEPS * IN_F) + (t + 1) * IN_F];
        }
        LBAR();   // h1s/xs/flags ready for next step
    }

    // ---- final linear: out = h1 @ Wlin + blin  (64x512 @ 512x19) ----
    for (int task = tid; task < BW * OUT_F; task += 1024) {
        int o   = task >> 6;     // 0..18, wave-uniform
        int row = task & 63;
        float s = blin[o];
        const float* wl = Wlin + o;
        for (int k = 0; k < HID; ++k) {
            int byte = row * 1024 + ((2 * k) ^ ((row & 7) << 4));
            float hv = __bfloat162float(*(const __hip_bfloat16*)((const char*)h1s + byte));
            s += hv * wl[k * OUT_F];
        }
        out[(bbase + row) * OUT_F + o] = s;
    }
}

extern "C" void kernel_launch(void* const* d_in, const int* in_sizes, int n_in,
                              void* d_out, int out_size, void* d_ws, size_t ws_size,
                              hipStream_t stream) {
    const float* x    = (const float*)d_in[0];
    const float* Wx0  = (const float*)d_in[1];
    const float* Wh0  = (const float*)d_in[2];
    const float* b0   = (const float*)d_in[3];
    const float* Wx1  = (const float*)d_in[4];
    const float* Wh1  = (const float*)d_in[5];
    const float* b1   = (const float*)d_in[6];
    const float* Wlin = (const float*)d_in[7];
    const float* blin = (const float*)d_in[8];

    // workspace carve (bytes)
    const size_t offWx0p  = 0;                       // 2048*64*2   = 262144
    const size_t offWh0p  = 262144;                  // 2048*512*2  = 2097152
    const size_t offWx1hp = 2359296;
    const size_t offWh1p  = 4456448;
    const size_t offC     = 6553600;                 // 2*256*32768*4 = 67108864
    const size_t offH     = 73662464;                // 67108864
    const size_t needed   = 140771328;
    if (ws_size < needed) return;

    char* w = (char*)d_ws;
    __hip_bfloat16* Wx0p  = (__hip_bfloat16*)(w + offWx0p);
    __hip_bfloat16* Wh0p  = (__hip_bfloat16*)(w + offWh0p);
    __hip_bfloat16* Wx1hp = (__hip_bfloat16*)(w + offWx1hp);
    __hip_bfloat16* Wh1p  = (__hip_bfloat16*)(w + offWh1p);
    float* cws = (float*)(w + offC);
    float* hws = (float*)(w + offH);

    dim3 blk(256);
    wprep_kernel<<<(2048 * 64 + 255) / 256, blk, 0, stream>>>(Wx0, Wx0p, 1, 0);
    wprep_kernel<<<(2048 * 512 + 255) / 256, blk, 0, stream>>>(Wh0, Wh0p, 4, 0);
    wprep_kernel<<<(2048 * 512 + 255) / 256, blk, 0, stream>>>(Wx1, Wx1hp, 4, 1);  // skip flag row
    wprep_kernel<<<(2048 * 512 + 255) / 256, blk, 0, stream>>>(Wh1, Wh1p, 4, 0);

    lstm_main<<<256, 1024, 0, stream>>>(x, b0, Wx1, b1, Wlin, blin,
                                        Wx0p, Wh0p, Wx1hp, Wh1p, cws, hws, (float*)d_out);
}